// Round 1
// baseline (468.028 us; speedup 1.0000x reference)
//
#include <hip/hip_runtime.h>

typedef __bf16 bf16x8 __attribute__((ext_vector_type(8)));
typedef float f32x4 __attribute__((ext_vector_type(4)));
typedef unsigned short us4 __attribute__((ext_vector_type(4)));
typedef unsigned short us8 __attribute__((ext_vector_type(8)));
typedef unsigned short u16;

#define DEVI __device__ __forceinline__

constexpr int B_ = 4, C_ = 256, N_ = 4096;

DEVI u16 f2bf(float f) {
  unsigned u = __builtin_bit_cast(unsigned, f);
  u += 0x7fffu + ((u >> 16) & 1u);
  return (u16)(u >> 16);
}
DEVI float bf2f(u16 h) { return __builtin_bit_cast(float, ((unsigned)h) << 16); }

#define MFMA16(a, b, c) __builtin_amdgcn_mfma_f32_16x16x32_bf16((a), (b), (c), 0, 0, 0)

// ---------------- kernel 0: weight conversion to bf16 hi/lo ----------------
__global__ __launch_bounds__(256, 1) void prep_weights(
    const float* __restrict__ wq, const float* __restrict__ wk,
    const float* __restrict__ wv, const float* __restrict__ wo,
    u16* __restrict__ wqh, u16* __restrict__ wql,
    u16* __restrict__ wkh, u16* __restrict__ wkl,
    u16* __restrict__ wvh, u16* __restrict__ woh) {
  int idx = blockIdx.x * 256 + threadIdx.x;
  float q = wq[idx];
  u16 qh = f2bf(q);
  wqh[idx] = qh;
  wql[idx] = f2bf(q - bf2f(qh));
  float k = wk[idx];
  u16 kh = f2bf(k);
  wkh[idx] = kh;
  wkl[idx] = f2bf(k - bf2f(kh));
  wvh[idx] = f2bf(wv[idx]);
  woh[idx] = f2bf(wo[idx]);
}

// ---------------- kernel 1: K (hi/lo, transposed) and V projections ----------------
__global__ __launch_bounds__(256, 1) void proj_kv(
    const float* __restrict__ ctx, const float* __restrict__ bk, const float* __restrict__ bv,
    const u16* __restrict__ wkh, const u16* __restrict__ wkl, const u16* __restrict__ wvh,
    u16* __restrict__ KTh, u16* __restrict__ KTl, u16* __restrict__ Vg) {
  const int blk = blockIdx.x;
  const int b = blk & 3;
  const int j0 = (blk >> 2) << 6;
  const int tid = threadIdx.x;
  const int lane = tid & 63;
  const int w = tid >> 6;
  const int l15 = lane & 15;
  const int g = lane >> 4;

  __shared__ alignas(16) u16 ldsH[64 * 256];
  __shared__ alignas(16) u16 ldsL[64 * 256];

  // stage ctx^T (hi/lo) into LDS [j][c], swizzled
  {
    const float* cb = ctx + (size_t)b * C_ * N_ + j0;
    #pragma unroll
    for (int it = 0; it < 16; ++it) {
      int idx = it * 256 + tid;
      int c = idx >> 4;
      int j4 = (idx & 15) << 2;
      float4 f = *(const float4*)(cb + (size_t)c * N_ + j4);
      float vv[4] = {f.x, f.y, f.z, f.w};
      #pragma unroll
      for (int e = 0; e < 4; ++e) {
        int j = j4 + e;
        u16 h = f2bf(vv[e]);
        int uidx = j * 256 + ((((c >> 3) ^ (j & 7))) << 3) + (c & 7);
        ldsH[uidx] = h;
        ldsL[uidx] = f2bf(vv[e] - bf2f(h));
      }
    }
  }
  __syncthreads();

  const int jloc = 16 * w + l15;  // this wave's key column (B-frag n = l15)
  bf16x8 ch[8], cl[8];
  #pragma unroll
  for (int ks = 0; ks < 8; ++ks) {
    int uidx = jloc * 256 + (((g + 4 * ks) ^ (jloc & 7)) << 3);
    ch[ks] = *(const bf16x8*)&ldsH[uidx];
    cl[ks] = *(const bf16x8*)&ldsL[uidx];
  }

  #pragma unroll 4
  for (int mt = 0; mt < 16; ++mt) {
    f32x4 ka = {0, 0, 0, 0}, ka2 = {0, 0, 0, 0}, va = {0, 0, 0, 0};
    #pragma unroll
    for (int ks = 0; ks < 8; ++ks) {
      int aoff = (16 * mt + l15) * 256 + 8 * g + 32 * ks;
      bf16x8 ah = *(const bf16x8*)(wkh + aoff);
      bf16x8 al = *(const bf16x8*)(wkl + aoff);
      bf16x8 av = *(const bf16x8*)(wvh + aoff);
      ka = MFMA16(ah, ch[ks], ka);
      ka2 = MFMA16(ah, cl[ks], ka2);
      ka2 = MFMA16(al, ch[ks], ka2);
      va = MFMA16(av, ch[ks], va);
    }
    int c0 = 16 * mt + 4 * g;
    float4 bk4 = *(const float4*)(bk + c0);
    float4 bv4 = *(const float4*)(bv + c0);
    us4 h4, l4;
    #pragma unroll
    for (int r = 0; r < 4; ++r) {
      float kv = ka[r] + ka2[r] + ((const float*)&bk4)[r];
      u16 hh = f2bf(kv);
      h4[r] = hh;
      l4[r] = f2bf(kv - bf2f(hh));
    }
    size_t krow = ((size_t)b * N_ + j0 + jloc) * C_ + c0;
    *(us4*)(KTh + krow) = h4;
    *(us4*)(KTl + krow) = l4;
    #pragma unroll
    for (int r = 0; r < 4; ++r) {
      float vv = va[r] + ((const float*)&bv4)[r];
      Vg[((size_t)b * C_ + c0 + r) * N_ + j0 + jloc] = f2bf(vv);
    }
  }
}

// ---------------- kernel 2: fused Q-proj + flash attention + O-proj + residual ----------------
__global__ __launch_bounds__(256, 1) void attn_fused(
    const float* __restrict__ x, const float* __restrict__ bq, const float* __restrict__ bo,
    const u16* __restrict__ wqh, const u16* __restrict__ wql, const u16* __restrict__ woh,
    const u16* __restrict__ KTh, const u16* __restrict__ KTl, const u16* __restrict__ Vg,
    float* __restrict__ out) {
  const int blk = blockIdx.x;
  const int b = blk & 3;              // XCD x serves batch x&3 -> K/V L2 locality
  const int i0 = (blk >> 2) << 6;
  const int tid = threadIdx.x;
  const int lane = tid & 63;
  const int w = tid >> 6;
  const int l15 = lane & 15;
  const int g = lane >> 4;

  __shared__ alignas(16) u16 ldsH[64 * 256];   // x^T hi -> Q hi -> K hi -> O
  __shared__ alignas(16) u16 ldsL[64 * 256];   // x^T lo -> Q lo -> K lo
  __shared__ alignas(16) u16 ldsV[256 * 64];
  __shared__ alignas(16) u16 ldsPT[4][64 * 20];
  __shared__ alignas(16) float ldsF[4][16];

  // ---- stage x^T hi/lo
  {
    const float* xb = x + (size_t)b * C_ * N_ + i0;
    #pragma unroll
    for (int it = 0; it < 16; ++it) {
      int idx = it * 256 + tid;
      int c = idx >> 4;
      int i4 = (idx & 15) << 2;
      float4 f = *(const float4*)(xb + (size_t)c * N_ + i4);
      float vv[4] = {f.x, f.y, f.z, f.w};
      #pragma unroll
      for (int e = 0; e < 4; ++e) {
        int i = i4 + e;
        u16 h = f2bf(vv[e]);
        int uidx = i * 256 + ((((c >> 3) ^ (i & 7))) << 3) + (c & 7);
        ldsH[uidx] = h;
        ldsL[uidx] = f2bf(vv[e] - bf2f(h));
      }
    }
  }
  __syncthreads();

  const int iloc = 16 * w + l15;  // this wave's query (0..63 within tile)

  bf16x8 xh[8], xl[8];
  #pragma unroll
  for (int ks = 0; ks < 8; ++ks) {
    int uidx = iloc * 256 + (((g + 4 * ks) ^ (iloc & 7)) << 3);
    xh[ks] = *(const bf16x8*)&ldsH[uidx];
    xl[ks] = *(const bf16x8*)&ldsL[uidx];
  }

  // Q = wq x + bq (3-term split)
  f32x4 qd[16];
  #pragma unroll
  for (int mt = 0; mt < 16; ++mt) {
    f32x4 a1 = {0, 0, 0, 0}, a2 = {0, 0, 0, 0};
    #pragma unroll
    for (int ks = 0; ks < 8; ++ks) {
      int aoff = (16 * mt + l15) * 256 + 8 * g + 32 * ks;
      bf16x8 ah = *(const bf16x8*)(wqh + aoff);
      bf16x8 al = *(const bf16x8*)(wql + aoff);
      a1 = MFMA16(ah, xh[ks], a1);
      a2 = MFMA16(ah, xl[ks], a2);
      a2 = MFMA16(al, xh[ks], a2);
    }
    int c0 = 16 * mt + 4 * g;
    float4 bq4 = *(const float4*)(bq + c0);
    #pragma unroll
    for (int r = 0; r < 4; ++r) qd[mt][r] = a1[r] + a2[r] + ((const float*)&bq4)[r];
  }
  __syncthreads();  // done reading x^T

  // write Q hi/lo transposed [i][c] (swizzled)
  #pragma unroll
  for (int mt = 0; mt < 16; ++mt) {
    int c0 = 16 * mt + 4 * g;
    us4 h4, l4;
    #pragma unroll
    for (int r = 0; r < 4; ++r) {
      u16 hh = f2bf(qd[mt][r]);
      h4[r] = hh;
      l4[r] = f2bf(qd[mt][r] - bf2f(hh));
    }
    int uidx = iloc * 256 + ((((c0 >> 3) ^ (iloc & 7))) << 3) + (c0 & 7);
    *(us4*)&ldsH[uidx] = h4;
    *(us4*)&ldsL[uidx] = l4;
  }
  __syncthreads();

  bf16x8 qh[8], ql[8];
  #pragma unroll
  for (int ks = 0; ks < 8; ++ks) {
    int uidx = iloc * 256 + (((g + 4 * ks) ^ (iloc & 7)) << 3);
    qh[ks] = *(const bf16x8*)&ldsH[uidx];
    ql[ks] = *(const bf16x8*)&ldsL[uidx];
  }
  __syncthreads();

  float mrun[4] = {-1e30f, -1e30f, -1e30f, -1e30f};
  float lrun[4] = {0, 0, 0, 0};
  f32x4 oacc[16];
  #pragma unroll
  for (int mt = 0; mt < 16; ++mt) oacc[mt] = (f32x4){0, 0, 0, 0};

  const u16* khg = KTh + (size_t)b * N_ * C_;
  const u16* klg = KTl + (size_t)b * N_ * C_;
  const u16* vg = Vg + (size_t)b * C_ * N_;

  for (int kv0 = 0; kv0 < N_; kv0 += 64) {
    // ---- stage K tile hi/lo (linear rows -> swizzled LDS)
    {
      const u16* src_h = khg + (size_t)kv0 * C_;
      const u16* src_l = klg + (size_t)kv0 * C_;
      #pragma unroll
      for (int it = 0; it < 8; ++it) {
        int idx = it * 256 + tid;
        int j = idx >> 5;
        int c8 = idx & 31;
        us8 dh = *(const us8*)(src_h + idx * 8);
        us8 dl = *(const us8*)(src_l + idx * 8);
        int uidx = j * 256 + ((c8 ^ (j & 7)) << 3);
        *(us8*)&ldsH[uidx] = dh;
        *(us8*)&ldsL[uidx] = dl;
      }
      #pragma unroll
      for (int it = 0; it < 8; ++it) {
        int idx = it * 256 + tid;
        int c = idx >> 3;
        int j8 = idx & 7;
        us8 dv = *(const us8*)(vg + (size_t)c * N_ + kv0 + j8 * 8);
        int uidx = c * 64 + ((j8 ^ (c & 7)) << 3);
        *(us8*)&ldsV[uidx] = dv;
      }
    }
    __syncthreads();

    // ---- S = Q^T K (split, two chains)
    f32x4 s1[4], s2[4];
    #pragma unroll
    for (int nt = 0; nt < 4; ++nt) {
      s1[nt] = (f32x4){0, 0, 0, 0};
      s2[nt] = (f32x4){0, 0, 0, 0};
    }
    #pragma unroll
    for (int ks = 0; ks < 8; ++ks) {
      bf16x8 bh[4], bl[4];
      #pragma unroll
      for (int nt = 0; nt < 4; ++nt) {
        int j = 16 * nt + l15;
        int uidx = j * 256 + (((g + 4 * ks) ^ (j & 7)) << 3);
        bh[nt] = *(const bf16x8*)&ldsH[uidx];
        bl[nt] = *(const bf16x8*)&ldsL[uidx];
      }
      #pragma unroll
      for (int nt = 0; nt < 4; ++nt) s1[nt] = MFMA16(qh[ks], bh[nt], s1[nt]);
      #pragma unroll
      for (int nt = 0; nt < 4; ++nt) s2[nt] = MFMA16(qh[ks], bl[nt], s2[nt]);
      #pragma unroll
      for (int nt = 0; nt < 4; ++nt) s2[nt] = MFMA16(ql[ks], bh[nt], s2[nt]);
    }
    #pragma unroll
    for (int nt = 0; nt < 4; ++nt) s1[nt] += s2[nt];

    // ---- online softmax (lane holds rows i=4g+r, cols j=l15+16nt)
    float tm[4];
    #pragma unroll
    for (int r = 0; r < 4; ++r) {
      tm[r] = fmaxf(fmaxf(s1[0][r], s1[1][r]), fmaxf(s1[2][r], s1[3][r]));
      #pragma unroll
      for (int msk = 1; msk < 16; msk <<= 1) tm[r] = fmaxf(tm[r], __shfl_xor(tm[r], msk));
    }
    float sc[4], rs[4];
    #pragma unroll
    for (int r = 0; r < 4; ++r) {
      float mn = fmaxf(mrun[r], tm[r]);
      sc[r] = __expf(mrun[r] - mn);
      mrun[r] = mn;
      rs[r] = 0.f;
    }
    #pragma unroll
    for (int nt = 0; nt < 4; ++nt) {
      #pragma unroll
      for (int r = 0; r < 4; ++r) {
        float p = __expf(s1[nt][r] - mrun[r]);
        s1[nt][r] = p;
        rs[r] += p;
      }
    }
    #pragma unroll
    for (int r = 0; r < 4; ++r) {
      #pragma unroll
      for (int msk = 1; msk < 16; msk <<= 1) rs[r] += __shfl_xor(rs[r], msk);
      lrun[r] = lrun[r] * sc[r] + rs[r];
    }
    // broadcast rescale factor to O layout (col index = l15)
    if (l15 == 0) {
      f32x4 t;
      t[0] = sc[0]; t[1] = sc[1]; t[2] = sc[2]; t[3] = sc[3];
      *(f32x4*)&ldsF[w][4 * g] = t;
    }
    float fsc = ldsF[w][l15];
    #pragma unroll
    for (int mt = 0; mt < 16; ++mt) oacc[mt] *= fsc;

    // ---- P -> per-wave PT buffer [j][i]
    #pragma unroll
    for (int nt = 0; nt < 4; ++nt) {
      us4 p4;
      #pragma unroll
      for (int r = 0; r < 4; ++r) p4[r] = f2bf(s1[nt][r]);
      int j = 16 * nt + l15;
      *(us4*)&ldsPT[w][j * 20 + 4 * g] = p4;
    }
    // ---- PV: O += V P^T
    bf16x8 pb[2];
    #pragma unroll
    for (int ks2 = 0; ks2 < 2; ++ks2) {
      us8 t;
      #pragma unroll
      for (int e = 0; e < 8; ++e) {
        int j = 8 * g + e + 32 * ks2;
        t[e] = ldsPT[w][j * 20 + l15];
      }
      pb[ks2] = __builtin_bit_cast(bf16x8, t);
    }
    #pragma unroll
    for (int ks2 = 0; ks2 < 2; ++ks2) {
      #pragma unroll
      for (int mt = 0; mt < 16; ++mt) {
        int c = 16 * mt + l15;
        int uidx = c * 64 + (((g + 4 * ks2) ^ (c & 7)) << 3);
        bf16x8 va = *(const bf16x8*)&ldsV[uidx];
        oacc[mt] = MFMA16(va, pb[ks2], oacc[mt]);
      }
    }
    __syncthreads();
  }

  // ---- normalize
  {
    float inv[4];
    #pragma unroll
    for (int r = 0; r < 4; ++r) inv[r] = 1.0f / lrun[r];
    if (l15 == 0) {
      f32x4 t;
      t[0] = inv[0]; t[1] = inv[1]; t[2] = inv[2]; t[3] = inv[3];
      *(f32x4*)&ldsF[w][4 * g] = t;
    }
    float fi = ldsF[w][l15];
    #pragma unroll
    for (int mt = 0; mt < 16; ++mt) oacc[mt] *= fi;
  }
  // ---- O (bf16) into ldsH [i][c] swizzled (own-wave rows only)
  #pragma unroll
  for (int mt = 0; mt < 16; ++mt) {
    int c0 = 16 * mt + 4 * g;
    us4 h4;
    #pragma unroll
    for (int r = 0; r < 4; ++r) h4[r] = f2bf(oacc[mt][r]);
    int uidx = iloc * 256 + ((((c0 >> 3) ^ (iloc & 7))) << 3) + (c0 & 7);
    *(us4*)&ldsH[uidx] = h4;
  }
  // ---- final projection + bias + residual
  f32x4 facc[16];
  #pragma unroll
  for (int mt = 0; mt < 16; ++mt) facc[mt] = (f32x4){0, 0, 0, 0};
  #pragma unroll
  for (int ks = 0; ks < 8; ++ks) {
    int uidx = iloc * 256 + (((g + 4 * ks) ^ (iloc & 7)) << 3);
    bf16x8 ob = *(const bf16x8*)&ldsH[uidx];
    #pragma unroll
    for (int mt = 0; mt < 16; ++mt) {
      bf16x8 ah = *(const bf16x8*)(woh + (16 * mt + l15) * 256 + 8 * g + 32 * ks);
      facc[mt] = MFMA16(ah, ob, facc[mt]);
    }
  }
  const int ig = i0 + iloc;
  #pragma unroll
  for (int mt = 0; mt < 16; ++mt) {
    int c0 = 16 * mt + 4 * g;
    float4 bo4 = *(const float4*)(bo + c0);
    #pragma unroll
    for (int r = 0; r < 4; ++r) {
      size_t off = ((size_t)b * C_ + c0 + r) * N_ + ig;
      out[off] = facc[mt][r] + ((const float*)&bo4)[r] + x[off];
    }
  }
}

extern "C" void kernel_launch(void* const* d_in, const int* in_sizes, int n_in,
                              void* d_out, int out_size, void* d_ws, size_t ws_size,
                              hipStream_t stream) {
  const float* x = (const float*)d_in[0];
  const float* ctx = (const float*)d_in[1];
  const float* wq = (const float*)d_in[2];
  const float* bq = (const float*)d_in[3];
  const float* wk = (const float*)d_in[4];
  const float* bk = (const float*)d_in[5];
  const float* wv = (const float*)d_in[6];
  const float* bv = (const float*)d_in[7];
  const float* wo = (const float*)d_in[8];
  const float* bo = (const float*)d_in[9];
  float* out = (float*)d_out;

  u16* ws = (u16*)d_ws;
  u16* wqh = ws;
  u16* wql = wqh + 65536;
  u16* wkh = wql + 65536;
  u16* wkl = wkh + 65536;
  u16* wvh = wkl + 65536;
  u16* woh = wvh + 65536;
  u16* KTh = woh + 65536;
  u16* KTl = KTh + (size_t)B_ * N_ * C_;
  u16* Vg = KTl + (size_t)B_ * N_ * C_;

  prep_weights<<<256, 256, 0, stream>>>(wq, wk, wv, wo, wqh, wql, wkh, wkl, wvh, woh);
  proj_kv<<<256, 256, 0, stream>>>(ctx, bk, bv, wkh, wkl, wvh, KTh, KTl, Vg);
  attn_fused<<<256, 256, 0, stream>>>(x, bq, bo, wqh, wql, woh, KTh, KTl, Vg, out);
}

// Round 8
// 397.530 us; speedup vs baseline: 1.1773x; 1.1773x over previous
//
#include <hip/hip_runtime.h>

typedef __bf16 bf16x8 __attribute__((ext_vector_type(8)));
typedef float f32x4 __attribute__((ext_vector_type(4)));
typedef unsigned short us4 __attribute__((ext_vector_type(4)));
typedef unsigned short us8 __attribute__((ext_vector_type(8)));
typedef unsigned short u16;

#define DEVI __device__ __forceinline__

constexpr int B_ = 4, C_ = 256, N_ = 4096;

DEVI u16 f2bf(float f) {
  unsigned u = __builtin_bit_cast(unsigned, f);
  u += 0x7fffu + ((u >> 16) & 1u);
  return (u16)(u >> 16);
}
DEVI float bf2f(u16 h) { return __builtin_bit_cast(float, ((unsigned)h) << 16); }

#define MFMA16(a, b, c) __builtin_amdgcn_mfma_f32_16x16x32_bf16((a), (b), (c), 0, 0, 0)

DEVI void gload16(const void* g, void* l) {
  __builtin_amdgcn_global_load_lds((const __attribute__((address_space(1))) void*)g,
                                   (__attribute__((address_space(3))) void*)l, 16, 0, 0);
}

// broadcast per-row value (rows 4g+r live in lanes of group g) to O layout (row idx = l15)
DEVI float bcast_row(float v0, float v1, float v2, float v3, int l15) {
  int src = (l15 >> 2) << 4;
  float a0 = __shfl(v0, src, 64);
  float a1 = __shfl(v1, src, 64);
  float a2 = __shfl(v2, src, 64);
  float a3 = __shfl(v3, src, 64);
  float x0 = (l15 & 1) ? a1 : a0;
  float x1 = (l15 & 1) ? a3 : a2;
  return (l15 & 2) ? x1 : x0;
}

// ---------------- kernel 0: weight conversion to bf16 hi/lo ----------------
__global__ __launch_bounds__(256, 1) void prep_weights(
    const float* __restrict__ wq, const float* __restrict__ wk,
    const float* __restrict__ wv, const float* __restrict__ wo,
    u16* __restrict__ wqh, u16* __restrict__ wql,
    u16* __restrict__ wkh, u16* __restrict__ wkl,
    u16* __restrict__ wvh, u16* __restrict__ woh) {
  int idx = blockIdx.x * 256 + threadIdx.x;
  float q = wq[idx];
  u16 qh = f2bf(q);
  wqh[idx] = qh;
  wql[idx] = f2bf(q - bf2f(qh));
  float k = wk[idx];
  u16 kh = f2bf(k);
  wkh[idx] = kh;
  wkl[idx] = f2bf(k - bf2f(kh));
  wvh[idx] = f2bf(wv[idx]);
  woh[idx] = f2bf(wo[idx]);
}

// ---------------- kernel 1: K (bf16, transposed) and V projections ----------------
__global__ __launch_bounds__(256, 2) void proj_kv(
    const float* __restrict__ ctx, const float* __restrict__ bk, const float* __restrict__ bv,
    const u16* __restrict__ wkh, const u16* __restrict__ wkl, const u16* __restrict__ wvh,
    u16* __restrict__ KTh, u16* __restrict__ Vg) {
  const int blk = blockIdx.x;
  const int b = blk & 3;
  const int j0 = (blk >> 2) << 6;
  const int tid = threadIdx.x;
  const int lane = tid & 63;
  const int w = tid >> 6;
  const int l15 = lane & 15;
  const int g = lane >> 4;

  __shared__ alignas(16) u16 ldsH[64 * 256];
  __shared__ alignas(16) u16 ldsL[64 * 256];

  // stage ctx^T (hi/lo) into LDS [j][c], swizzled
  {
    const float* cb = ctx + (size_t)b * C_ * N_ + j0;
    #pragma unroll
    for (int it = 0; it < 16; ++it) {
      int idx = it * 256 + tid;
      int c = idx >> 4;
      int j4 = (idx & 15) << 2;
      float4 f = *(const float4*)(cb + (size_t)c * N_ + j4);
      float vv[4] = {f.x, f.y, f.z, f.w};
      #pragma unroll
      for (int e = 0; e < 4; ++e) {
        int j = j4 + e;
        u16 h = f2bf(vv[e]);
        int uidx = j * 256 + ((((c >> 3) ^ (j & 7))) << 3) + (c & 7);
        ldsH[uidx] = h;
        ldsL[uidx] = f2bf(vv[e] - bf2f(h));
      }
    }
  }
  __syncthreads();

  const int jloc = 16 * w + l15;
  bf16x8 ch[8], cl[8];
  #pragma unroll
  for (int ks = 0; ks < 8; ++ks) {
    int uidx = jloc * 256 + (((g + 4 * ks) ^ (jloc & 7)) << 3);
    ch[ks] = *(const bf16x8*)&ldsH[uidx];
    cl[ks] = *(const bf16x8*)&ldsL[uidx];
  }

  #pragma unroll 4
  for (int mt = 0; mt < 16; ++mt) {
    f32x4 ka = {0, 0, 0, 0}, ka2 = {0, 0, 0, 0}, va = {0, 0, 0, 0};
    #pragma unroll
    for (int ks = 0; ks < 8; ++ks) {
      int aoff = (16 * mt + l15) * 256 + 8 * g + 32 * ks;
      bf16x8 ah = *(const bf16x8*)(wkh + aoff);
      bf16x8 al = *(const bf16x8*)(wkl + aoff);
      bf16x8 av = *(const bf16x8*)(wvh + aoff);
      ka = MFMA16(ah, ch[ks], ka);
      ka2 = MFMA16(ah, cl[ks], ka2);
      ka2 = MFMA16(al, ch[ks], ka2);
      va = MFMA16(av, ch[ks], va);
    }
    int c0 = 16 * mt + 4 * g;
    float4 bk4 = *(const float4*)(bk + c0);
    float4 bv4 = *(const float4*)(bv + c0);
    us4 h4;
    #pragma unroll
    for (int r = 0; r < 4; ++r) h4[r] = f2bf(ka[r] + ka2[r] + ((const float*)&bk4)[r]);
    *(us4*)(KTh + ((size_t)b * N_ + j0 + jloc) * C_ + c0) = h4;
    #pragma unroll
    for (int r = 0; r < 4; ++r) {
      float vv = va[r] + ((const float*)&bv4)[r];
      Vg[((size_t)b * C_ + c0 + r) * N_ + j0 + jloc] = f2bf(vv);
    }
  }
}

// ---- async staging helpers: linear LDS dest, inverse-swizzled global source ----
DEVI void stageK(const u16* khg, int kv0, u16* ldsK, int w, int lane) {
  #pragma unroll
  for (int t = 0; t < 8; ++t) {
    int L = t * 256 + w * 64 + lane;
    int j = L >> 5, s = L & 31;
    const u16* src = khg + (size_t)(kv0 + j) * C_ + ((s ^ (j & 7)) << 3);
    gload16(src, ldsK + (size_t)(t * 256 + w * 64) * 8);
  }
}
DEVI void stageV(const u16* vg, int kv0, u16* ldsV, int w, int lane) {
  #pragma unroll
  for (int t = 0; t < 8; ++t) {
    int L = t * 256 + w * 64 + lane;
    int c = L >> 3, sl = L & 7;
    const u16* src = vg + (size_t)c * N_ + kv0 + ((sl ^ (c & 7)) << 3);
    gload16(src, ldsV + (size_t)(t * 256 + w * 64) * 8);
  }
}

// ---------------- kernel 2: fused Q-proj + flash attention + O-proj + residual ----------------
__global__ __launch_bounds__(256, 2) void attn_fused(
    const float* __restrict__ x, const float* __restrict__ bq, const float* __restrict__ bo,
    const u16* __restrict__ wqh, const u16* __restrict__ wql, const u16* __restrict__ woh,
    const u16* __restrict__ KTh, const u16* __restrict__ Vg,
    float* __restrict__ out) {
  const int blk = blockIdx.x;
  const int b = (blk & 7) >> 1;                        // XCD x -> batch x>>1 (K/V fits L2)
  const int i0 = (((blk >> 3) << 1) | (blk & 1)) << 6;
  const int tid = threadIdx.x;
  const int lane = tid & 63;
  const int w = tid >> 6;
  const int l15 = lane & 15;
  const int g = lane >> 4;

  __shared__ alignas(16) char smem[74752];
  u16* ldsK = (u16*)smem;             // prologue: x/Q hi ; loop: K tile [64][256] swz
  u16* ldsV = (u16*)(smem + 32768);   // prologue: x/Q lo ; loop: V tile [256][64] swz
  u16* ldsPT = (u16*)(smem + 65536);  // per-wave P^T as [i][72-stride j]

  // ---- stage x^T hi/lo
  {
    const float* xb = x + (size_t)b * C_ * N_ + i0;
    #pragma unroll
    for (int it = 0; it < 16; ++it) {
      int idx = it * 256 + tid;
      int c = idx >> 4;
      int i4 = (idx & 15) << 2;
      float4 f = *(const float4*)(xb + (size_t)c * N_ + i4);
      float vv[4] = {f.x, f.y, f.z, f.w};
      #pragma unroll
      for (int e = 0; e < 4; ++e) {
        int i = i4 + e;
        u16 h = f2bf(vv[e]);
        int uidx = i * 256 + ((((c >> 3) ^ (i & 7))) << 3) + (c & 7);
        ldsK[uidx] = h;
        ldsV[uidx] = f2bf(vv[e] - bf2f(h));
      }
    }
  }
  __syncthreads();

  const int iloc = 16 * w + l15;

  bf16x8 xh[8], xl[8];
  #pragma unroll
  for (int ks = 0; ks < 8; ++ks) {
    int uidx = iloc * 256 + (((g + 4 * ks) ^ (iloc & 7)) << 3);
    xh[ks] = *(const bf16x8*)&ldsK[uidx];
    xl[ks] = *(const bf16x8*)&ldsV[uidx];
  }

  // Q = wq x + bq (3-term split)
  f32x4 qd[16];
  #pragma unroll
  for (int mt = 0; mt < 16; ++mt) {
    f32x4 a1 = {0, 0, 0, 0}, a2 = {0, 0, 0, 0};
    #pragma unroll
    for (int ks = 0; ks < 8; ++ks) {
      int aoff = (16 * mt + l15) * 256 + 8 * g + 32 * ks;
      bf16x8 ah = *(const bf16x8*)(wqh + aoff);
      bf16x8 al = *(const bf16x8*)(wql + aoff);
      a1 = MFMA16(ah, xh[ks], a1);
      a2 = MFMA16(ah, xl[ks], a2);
      a2 = MFMA16(al, xh[ks], a2);
    }
    int c0 = 16 * mt + 4 * g;
    float4 bq4 = *(const float4*)(bq + c0);
    #pragma unroll
    for (int r = 0; r < 4; ++r) qd[mt][r] = a1[r] + a2[r] + ((const float*)&bq4)[r];
  }
  __syncthreads();

  // write Q hi/lo transposed [i][c] (swizzled), read back A-fragments
  #pragma unroll
  for (int mt = 0; mt < 16; ++mt) {
    int c0 = 16 * mt + 4 * g;
    us4 h4, l4;
    #pragma unroll
    for (int r = 0; r < 4; ++r) {
      u16 hh = f2bf(qd[mt][r]);
      h4[r] = hh;
      l4[r] = f2bf(qd[mt][r] - bf2f(hh));
    }
    int uidx = iloc * 256 + ((((c0 >> 3) ^ (iloc & 7))) << 3) + (c0 & 7);
    *(us4*)&ldsK[uidx] = h4;
    *(us4*)&ldsV[uidx] = l4;
  }
  __syncthreads();

  bf16x8 qh[8], ql[8];
  #pragma unroll
  for (int ks = 0; ks < 8; ++ks) {
    int uidx = iloc * 256 + (((g + 4 * ks) ^ (iloc & 7)) << 3);
    qh[ks] = *(const bf16x8*)&ldsK[uidx];
    ql[ks] = *(const bf16x8*)&ldsV[uidx];
  }
  __syncthreads();

  const u16* khg = KTh + (size_t)b * N_ * C_;
  const u16* vg = Vg + (size_t)b * C_ * N_;

  stageK(khg, 0, ldsK, w, lane);
  stageV(vg, 0, ldsV, w, lane);

  float mrun[4] = {-1e30f, -1e30f, -1e30f, -1e30f};
  float lrun[4] = {0, 0, 0, 0};
  f32x4 oacc[16];
  #pragma unroll
  for (int mt = 0; mt < 16; ++mt) oacc[mt] = (f32x4){0, 0, 0, 0};

  __syncthreads();

  for (int kv0 = 0; kv0 < N_; kv0 += 64) {
    // ---- S = (Qh+Ql) K  (two chains)
    f32x4 s1[4], s2[4];
    #pragma unroll
    for (int nt = 0; nt < 4; ++nt) {
      s1[nt] = (f32x4){0, 0, 0, 0};
      s2[nt] = (f32x4){0, 0, 0, 0};
    }
    #pragma unroll
    for (int ks = 0; ks < 8; ++ks) {
      bf16x8 bh[4];
      #pragma unroll
      for (int nt = 0; nt < 4; ++nt) {
        int j = 16 * nt + l15;
        bh[nt] = *(const bf16x8*)&ldsK[j * 256 + (((g + 4 * ks) ^ (j & 7)) << 3)];
      }
      #pragma unroll
      for (int nt = 0; nt < 4; ++nt) s1[nt] = MFMA16(qh[ks], bh[nt], s1[nt]);
      #pragma unroll
      for (int nt = 0; nt < 4; ++nt) s2[nt] = MFMA16(ql[ks], bh[nt], s2[nt]);
    }
    #pragma unroll
    for (int nt = 0; nt < 4; ++nt) s1[nt] += s2[nt];

    // ---- online softmax with T13 defer-rescale (THR=6)
    float tm[4];
    #pragma unroll
    for (int r = 0; r < 4; ++r) {
      tm[r] = fmaxf(fmaxf(s1[0][r], s1[1][r]), fmaxf(s1[2][r], s1[3][r]));
      #pragma unroll
      for (int msk = 1; msk < 16; msk <<= 1) tm[r] = fmaxf(tm[r], __shfl_xor(tm[r], msk));
    }
    bool grow = (tm[0] > mrun[0] + 6.f) | (tm[1] > mrun[1] + 6.f) |
                (tm[2] > mrun[2] + 6.f) | (tm[3] > mrun[3] + 6.f);
    float sc[4];
    int need = __any((int)grow);
    if (need) {
      #pragma unroll
      for (int r = 0; r < 4; ++r) {
        float mn = fmaxf(mrun[r], tm[r]);
        sc[r] = __expf(mrun[r] - mn);
        mrun[r] = mn;
      }
      float fsc = bcast_row(sc[0], sc[1], sc[2], sc[3], l15);
      #pragma unroll
      for (int mt = 0; mt < 16; ++mt) oacc[mt] *= fsc;
    }
    float rs[4] = {0, 0, 0, 0};
    #pragma unroll
    for (int nt = 0; nt < 4; ++nt) {
      #pragma unroll
      for (int r = 0; r < 4; ++r) {
        float p = __expf(s1[nt][r] - mrun[r]);
        s1[nt][r] = p;
        rs[r] += p;
      }
    }
    #pragma unroll
    for (int r = 0; r < 4; ++r) {
      #pragma unroll
      for (int msk = 1; msk < 16; msk <<= 1) rs[r] += __shfl_xor(rs[r], msk);
      lrun[r] = need ? lrun[r] * sc[r] + rs[r] : lrun[r] + rs[r];
    }

    // ---- P^T into per-wave [i][j] buffer (stride 72)
    #pragma unroll
    for (int nt = 0; nt < 4; ++nt) {
      int jcol = 16 * nt + l15;
      #pragma unroll
      for (int r = 0; r < 4; ++r) ldsPT[w * 1152 + (4 * g + r) * 72 + jcol] = f2bf(s1[nt][r]);
    }

    __syncthreads();  // A: all waves done reading ldsK
    if (kv0 + 64 < N_) stageK(khg, kv0 + 64, ldsK, w, lane);  // overlaps PV

    // ---- PV: O += V P^T
    bf16x8 pb[2];
    #pragma unroll
    for (int ks2 = 0; ks2 < 2; ++ks2)
      pb[ks2] = *(const bf16x8*)&ldsPT[w * 1152 + l15 * 72 + 8 * (g + 4 * ks2)];
    #pragma unroll
    for (int ks2 = 0; ks2 < 2; ++ks2) {
      #pragma unroll
      for (int mt = 0; mt < 16; ++mt) {
        int c = 16 * mt + l15;
        bf16x8 va = *(const bf16x8*)&ldsV[c * 64 + (((g + 4 * ks2) ^ (c & 7)) << 3)];
        oacc[mt] = MFMA16(va, pb[ks2], oacc[mt]);
      }
    }

    __syncthreads();  // B: all waves done reading ldsV; K(t+1) landed
    if (kv0 + 64 < N_) stageV(vg, kv0 + 64, ldsV, w, lane);  // overlaps next QK
  }

  // ---- normalize
  {
    float inv[4];
    #pragma unroll
    for (int r = 0; r < 4; ++r) inv[r] = 1.0f / lrun[r];
    float fi = bcast_row(inv[0], inv[1], inv[2], inv[3], l15);
    #pragma unroll
    for (int mt = 0; mt < 16; ++mt) oacc[mt] *= fi;
  }
  // ---- O (bf16) into ldsK [i][c] swizzled (per-wave disjoint rows)
  #pragma unroll
  for (int mt = 0; mt < 16; ++mt) {
    int c0 = 16 * mt + 4 * g;
    us4 h4;
    #pragma unroll
    for (int r = 0; r < 4; ++r) h4[r] = f2bf(oacc[mt][r]);
    int uidx = iloc * 256 + ((((c0 >> 3) ^ (iloc & 7))) << 3) + (c0 & 7);
    *(us4*)&ldsK[uidx] = h4;
  }
  // ---- final projection + bias + residual
  f32x4 facc[16];
  #pragma unroll
  for (int mt = 0; mt < 16; ++mt) facc[mt] = (f32x4){0, 0, 0, 0};
  #pragma unroll
  for (int ks = 0; ks < 8; ++ks) {
    bf16x8 ob = *(const bf16x8*)&ldsK[iloc * 256 + (((g + 4 * ks) ^ (iloc & 7)) << 3)];
    #pragma unroll
    for (int mt = 0; mt < 16; ++mt) {
      bf16x8 ah = *(const bf16x8*)(woh + (16 * mt + l15) * 256 + 8 * g + 32 * ks);
      facc[mt] = MFMA16(ah, ob, facc[mt]);
    }
  }
  const int ig = i0 + iloc;
  #pragma unroll
  for (int mt = 0; mt < 16; ++mt) {
    int c0 = 16 * mt + 4 * g;
    float4 bo4 = *(const float4*)(bo + c0);
    #pragma unroll
    for (int r = 0; r < 4; ++r) {
      size_t off = ((size_t)b * C_ + c0 + r) * N_ + ig;
      out[off] = facc[mt][r] + ((const float*)&bo4)[r] + x[off];
    }
  }
}

extern "C" void kernel_launch(void* const* d_in, const int* in_sizes, int n_in,
                              void* d_out, int out_size, void* d_ws, size_t ws_size,
                              hipStream_t stream) {
  const float* x = (const float*)d_in[0];
  const float* ctx = (const float*)d_in[1];
  const float* wq = (const float*)d_in[2];
  const float* bq = (const float*)d_in[3];
  const float* wk = (const float*)d_in[4];
  const float* bk = (const float*)d_in[5];
  const float* wv = (const float*)d_in[6];
  const float* bv = (const float*)d_in[7];
  const float* wo = (const float*)d_in[8];
  const float* bo = (const float*)d_in[9];
  float* out = (float*)d_out;

  u16* ws = (u16*)d_ws;
  u16* wqh = ws;
  u16* wql = wqh + 65536;
  u16* wkh = wql + 65536;
  u16* wkl = wkh + 65536;
  u16* wvh = wkl + 65536;
  u16* woh = wvh + 65536;
  u16* KTh = woh + 65536;
  u16* Vg = KTh + (size_t)B_ * N_ * C_;

  prep_weights<<<256, 256, 0, stream>>>(wq, wk, wv, wo, wqh, wql, wkh, wkl, wvh, woh);
  proj_kv<<<256, 256, 0, stream>>>(ctx, bk, bv, wkh, wkl, wvh, KTh, Vg);
  attn_fused<<<256, 256, 0, stream>>>(x, bq, bo, wqh, wql, woh, KTh, Vg, out);
}

// Round 14
// 354.572 us; speedup vs baseline: 1.3200x; 1.1212x over previous
//
#include <hip/hip_runtime.h>

typedef _Float16 f16;
typedef _Float16 f16x8 __attribute__((ext_vector_type(8)));
typedef _Float16 f16x4 __attribute__((ext_vector_type(4)));
typedef float f32x4 __attribute__((ext_vector_type(4)));

#define DEVI __device__ __forceinline__

constexpr int B_ = 4, C_ = 256, N_ = 4096;

#define MFMAH(a, b, c) __builtin_amdgcn_mfma_f32_16x16x32_f16((a), (b), (c), 0, 0, 0)

DEVI void gload16(const void* g, void* l) {
  __builtin_amdgcn_global_load_lds((const __attribute__((address_space(1))) void*)g,
                                   (__attribute__((address_space(3))) void*)l, 16, 0, 0);
}

// broadcast per-row value (rows 4g+r live in lanes of group g) to O layout (row idx = l15)
DEVI float bcast_row(float v0, float v1, float v2, float v3, int l15) {
  int src = (l15 >> 2) << 4;
  float a0 = __shfl(v0, src, 64);
  float a1 = __shfl(v1, src, 64);
  float a2 = __shfl(v2, src, 64);
  float a3 = __shfl(v3, src, 64);
  float x0 = (l15 & 1) ? a1 : a0;
  float x1 = (l15 & 1) ? a3 : a2;
  return (l15 & 2) ? x1 : x0;
}

// ---------------- kernel 0: weight conversion to fp16 ----------------
__global__ __launch_bounds__(256, 1) void prep_weights(
    const float* __restrict__ wq, const float* __restrict__ wk,
    const float* __restrict__ wv, const float* __restrict__ wo,
    f16* __restrict__ wqh, f16* __restrict__ wkh,
    f16* __restrict__ wvh, f16* __restrict__ woh) {
  int idx = blockIdx.x * 256 + threadIdx.x;
  wqh[idx] = (f16)wq[idx];
  wkh[idx] = (f16)wk[idx];
  wvh[idx] = (f16)wv[idx];
  woh[idx] = (f16)wo[idx];
}

// ---------------- kernel 1: K (fp16, transposed) and V projections ----------------
__global__ __launch_bounds__(256, 2) void proj_kv(
    const float* __restrict__ ctx, const float* __restrict__ bk, const float* __restrict__ bv,
    const f16* __restrict__ wkh, const f16* __restrict__ wvh,
    f16* __restrict__ KTh, f16* __restrict__ Vg) {
  const int blk = blockIdx.x;
  const int b = blk & 3;
  const int j0 = (blk >> 2) << 6;
  const int tid = threadIdx.x;
  const int lane = tid & 63;
  const int w = tid >> 6;
  const int l15 = lane & 15;
  const int g = lane >> 4;

  __shared__ alignas(16) f16 ldsC[64 * 256];

  // stage ctx^T (fp16) into LDS [j][c], swizzled
  {
    const float* cb = ctx + (size_t)b * C_ * N_ + j0;
    #pragma unroll
    for (int it = 0; it < 16; ++it) {
      int idx = it * 256 + tid;
      int c = idx >> 4;
      int j4 = (idx & 15) << 2;
      float4 f = *(const float4*)(cb + (size_t)c * N_ + j4);
      float vv[4] = {f.x, f.y, f.z, f.w};
      #pragma unroll
      for (int e = 0; e < 4; ++e) {
        int j = j4 + e;
        int uidx = j * 256 + ((((c >> 3) ^ (j & 7))) << 3) + (c & 7);
        ldsC[uidx] = (f16)vv[e];
      }
    }
  }
  __syncthreads();

  const int jloc = 16 * w + l15;
  f16x8 ch[8];
  #pragma unroll
  for (int ks = 0; ks < 8; ++ks)
    ch[ks] = *(const f16x8*)&ldsC[jloc * 256 + (((g + 4 * ks) ^ (jloc & 7)) << 3)];

  #pragma unroll 4
  for (int mt = 0; mt < 16; ++mt) {
    f32x4 ka = {0, 0, 0, 0}, va = {0, 0, 0, 0};
    #pragma unroll
    for (int ks = 0; ks < 8; ++ks) {
      int aoff = (16 * mt + l15) * 256 + 8 * g + 32 * ks;
      f16x8 ah = *(const f16x8*)(wkh + aoff);
      f16x8 av = *(const f16x8*)(wvh + aoff);
      ka = MFMAH(ah, ch[ks], ka);
      va = MFMAH(av, ch[ks], va);
    }
    int c0 = 16 * mt + 4 * g;
    float4 bk4 = *(const float4*)(bk + c0);
    float4 bv4 = *(const float4*)(bv + c0);
    f16x4 h4;
    #pragma unroll
    for (int r = 0; r < 4; ++r) h4[r] = (f16)(ka[r] + ((const float*)&bk4)[r]);
    *(f16x4*)(KTh + ((size_t)b * N_ + j0 + jloc) * C_ + c0) = h4;
    #pragma unroll
    for (int r = 0; r < 4; ++r) {
      float vv = va[r] + ((const float*)&bv4)[r];
      Vg[((size_t)b * C_ + c0 + r) * N_ + j0 + jloc] = (f16)vv;
    }
  }
}

// ---- async staging helpers: linear LDS dest, inverse-swizzled global source ----
DEVI void stageK(const f16* khg, int kv0, f16* ldsK, int w, int lane) {
  #pragma unroll
  for (int t = 0; t < 8; ++t) {
    int L = t * 256 + w * 64 + lane;
    int j = L >> 5, s = L & 31;
    const f16* src = khg + (size_t)(kv0 + j) * C_ + ((s ^ (j & 7)) << 3);
    gload16(src, ldsK + (size_t)(t * 256 + w * 64) * 8);
  }
}
DEVI void stageV(const f16* vg, int kv0, f16* ldsV, int w, int lane) {
  #pragma unroll
  for (int t = 0; t < 8; ++t) {
    int L = t * 256 + w * 64 + lane;
    int c = L >> 3, sl = L & 7;
    const f16* src = vg + (size_t)c * N_ + kv0 + ((sl ^ (c & 7)) << 3);
    gload16(src, ldsV + (size_t)(t * 256 + w * 64) * 8);
  }
}

// ---------------- kernel 2: fused Q-proj + flash attention + O-proj + residual ----------------
__global__ __launch_bounds__(256, 1) void attn_fused(
    const float* __restrict__ x, const float* __restrict__ bq, const float* __restrict__ bo,
    const f16* __restrict__ wqh, const f16* __restrict__ woh,
    const f16* __restrict__ KTh, const f16* __restrict__ Vg,
    float* __restrict__ out) {
  const int blk = blockIdx.x;
  const int b = (blk & 7) >> 1;                        // XCD x -> batch x>>1 (K/V fits L2)
  const int i0 = (((blk >> 3) << 1) | (blk & 1)) << 6;
  const int tid = threadIdx.x;
  const int lane = tid & 63;
  const int w = tid >> 6;
  const int l15 = lane & 15;
  const int g = lane >> 4;

  __shared__ alignas(16) char smem[140288];
  f16* ldsK0 = (f16*)smem;              // K tile dbuf 0 (prologue: x / Q / O staging)
  f16* ldsK1 = (f16*)(smem + 32768);    // K tile dbuf 1
  f16* ldsV0 = (f16*)(smem + 65536);    // V tile dbuf 0
  f16* ldsV1 = (f16*)(smem + 98304);    // V tile dbuf 1
  f16* ldsPT = (f16*)(smem + 131072);   // per-wave P^T [i][72-stride j]

  // ---- stage x^T fp16 into ldsK0 [i][c] swizzled
  {
    const float* xb = x + (size_t)b * C_ * N_ + i0;
    #pragma unroll
    for (int it = 0; it < 16; ++it) {
      int idx = it * 256 + tid;
      int c = idx >> 4;
      int i4 = (idx & 15) << 2;
      float4 f = *(const float4*)(xb + (size_t)c * N_ + i4);
      float vv[4] = {f.x, f.y, f.z, f.w};
      #pragma unroll
      for (int e = 0; e < 4; ++e) {
        int i = i4 + e;
        int uidx = i * 256 + ((((c >> 3) ^ (i & 7))) << 3) + (c & 7);
        ldsK0[uidx] = (f16)vv[e];
      }
    }
  }
  __syncthreads();

  const int iloc = 16 * w + l15;

  f16x8 xh[8];
  #pragma unroll
  for (int ks = 0; ks < 8; ++ks)
    xh[ks] = *(const f16x8*)&ldsK0[iloc * 256 + (((g + 4 * ks) ^ (iloc & 7)) << 3)];

  // Q = wq x + bq (single fp16 chain)
  f32x4 qd[16];
  #pragma unroll
  for (int mt = 0; mt < 16; ++mt) {
    f32x4 a1 = {0, 0, 0, 0};
    #pragma unroll
    for (int ks = 0; ks < 8; ++ks) {
      f16x8 ah = *(const f16x8*)(wqh + (16 * mt + l15) * 256 + 8 * g + 32 * ks);
      a1 = MFMAH(ah, xh[ks], a1);
    }
    int c0 = 16 * mt + 4 * g;
    float4 bq4 = *(const float4*)(bq + c0);
    #pragma unroll
    for (int r = 0; r < 4; ++r) qd[mt][r] = a1[r] + ((const float*)&bq4)[r];
  }
  __syncthreads();  // done reading x

  // write Q fp16 transposed [i][c] (swizzled), read back A-fragments
  #pragma unroll
  for (int mt = 0; mt < 16; ++mt) {
    int c0 = 16 * mt + 4 * g;
    f16x4 h4;
    #pragma unroll
    for (int r = 0; r < 4; ++r) h4[r] = (f16)qd[mt][r];
    *(f16x4*)&ldsK0[iloc * 256 + ((((c0 >> 3) ^ (iloc & 7))) << 3) + (c0 & 7)] = h4;
  }
  __syncthreads();

  f16x8 qh[8];
  #pragma unroll
  for (int ks = 0; ks < 8; ++ks)
    qh[ks] = *(const f16x8*)&ldsK0[iloc * 256 + (((g + 4 * ks) ^ (iloc & 7)) << 3)];
  __syncthreads();  // all waves done reading Q before staging overwrites

  const f16* khg = KTh + (size_t)b * N_ * C_;
  const f16* vg = Vg + (size_t)b * C_ * N_;

  float mrun[4] = {-1e30f, -1e30f, -1e30f, -1e30f};
  float lrun[4] = {0, 0, 0, 0};
  f32x4 oacc[16];
  #pragma unroll
  for (int mt = 0; mt < 16; ++mt) oacc[mt] = (f32x4){0, 0, 0, 0};

  stageK(khg, 0, ldsK0, w, lane);
  stageV(vg, 0, ldsV0, w, lane);
  __syncthreads();  // drain tile 0

  for (int t = 0; t < 64; ++t) {
    const int kv0 = t << 6;
    f16* Kc = (t & 1) ? ldsK1 : ldsK0;
    f16* Vc = (t & 1) ? ldsV1 : ldsV0;
    f16* Kn = (t & 1) ? ldsK0 : ldsK1;
    f16* Vn = (t & 1) ? ldsV0 : ldsV1;

    // issue next-tile staging FIRST: hides under this whole iteration
    if (t < 63) {
      stageK(khg, kv0 + 64, Kn, w, lane);
      stageV(vg, kv0 + 64, Vn, w, lane);
    }

    // ---- S = Q K (single chain)
    f32x4 s1[4];
    #pragma unroll
    for (int nt = 0; nt < 4; ++nt) s1[nt] = (f32x4){0, 0, 0, 0};
    #pragma unroll
    for (int ks = 0; ks < 8; ++ks) {
      f16x8 bh[4];
      #pragma unroll
      for (int nt = 0; nt < 4; ++nt) {
        int j = 16 * nt + l15;
        bh[nt] = *(const f16x8*)&Kc[j * 256 + (((g + 4 * ks) ^ (j & 7)) << 3)];
      }
      #pragma unroll
      for (int nt = 0; nt < 4; ++nt) s1[nt] = MFMAH(qh[ks], bh[nt], s1[nt]);
    }

    // ---- online softmax with defer-rescale (THR=6)
    float tm[4];
    #pragma unroll
    for (int r = 0; r < 4; ++r) {
      tm[r] = fmaxf(fmaxf(s1[0][r], s1[1][r]), fmaxf(s1[2][r], s1[3][r]));
      #pragma unroll
      for (int msk = 1; msk < 16; msk <<= 1) tm[r] = fmaxf(tm[r], __shfl_xor(tm[r], msk));
    }
    bool grow = (tm[0] > mrun[0] + 6.f) | (tm[1] > mrun[1] + 6.f) |
                (tm[2] > mrun[2] + 6.f) | (tm[3] > mrun[3] + 6.f);
    float sc[4] = {1.f, 1.f, 1.f, 1.f};
    int need = __any((int)grow);
    if (need) {
      #pragma unroll
      for (int r = 0; r < 4; ++r) {
        float mn = fmaxf(mrun[r], tm[r]);
        sc[r] = __expf(mrun[r] - mn);
        mrun[r] = mn;
      }
      float fsc = bcast_row(sc[0], sc[1], sc[2], sc[3], l15);
      #pragma unroll
      for (int mt = 0; mt < 16; ++mt) oacc[mt] *= fsc;
    }
    float rs[4] = {0, 0, 0, 0};
    #pragma unroll
    for (int nt = 0; nt < 4; ++nt) {
      #pragma unroll
      for (int r = 0; r < 4; ++r) {
        float p = __expf(s1[nt][r] - mrun[r]);
        s1[nt][r] = p;
        rs[r] += p;
      }
    }
    #pragma unroll
    for (int r = 0; r < 4; ++r) {
      #pragma unroll
      for (int msk = 1; msk < 16; msk <<= 1) rs[r] += __shfl_xor(rs[r], msk);
      lrun[r] = need ? lrun[r] * sc[r] + rs[r] : lrun[r] + rs[r];
    }

    // ---- P^T into per-wave [i][j] buffer (stride 72) — wave-local, no barrier
    #pragma unroll
    for (int nt = 0; nt < 4; ++nt) {
      int jcol = 16 * nt + l15;
      #pragma unroll
      for (int r = 0; r < 4; ++r) ldsPT[w * 1152 + (4 * g + r) * 72 + jcol] = (f16)s1[nt][r];
    }
    f16x8 pb[2];
    #pragma unroll
    for (int ks2 = 0; ks2 < 2; ++ks2)
      pb[ks2] = *(const f16x8*)&ldsPT[w * 1152 + l15 * 72 + 8 * (g + 4 * ks2)];

    // ---- PV: O += V P^T
    #pragma unroll
    for (int ks2 = 0; ks2 < 2; ++ks2) {
      #pragma unroll
      for (int mt = 0; mt < 16; ++mt) {
        int c = 16 * mt + l15;
        f16x8 va = *(const f16x8*)&Vc[c * 64 + (((g + 4 * ks2) ^ (c & 7)) << 3)];
        oacc[mt] = MFMAH(va, pb[ks2], oacc[mt]);
      }
    }

    __syncthreads();  // single barrier/tile: cur bufs free + next-tile loads drained
  }

  // ---- normalize
  {
    float inv[4];
    #pragma unroll
    for (int r = 0; r < 4; ++r) inv[r] = 1.0f / lrun[r];
    float fi = bcast_row(inv[0], inv[1], inv[2], inv[3], l15);
    #pragma unroll
    for (int mt = 0; mt < 16; ++mt) oacc[mt] *= fi;
  }
  // ---- O (fp16) into ldsK0 [i][c] swizzled
  #pragma unroll
  for (int mt = 0; mt < 16; ++mt) {
    int c0 = 16 * mt + 4 * g;
    f16x4 h4;
    #pragma unroll
    for (int r = 0; r < 4; ++r) h4[r] = (f16)oacc[mt][r];
    *(f16x4*)&ldsK0[iloc * 256 + ((((c0 >> 3) ^ (iloc & 7))) << 3) + (c0 & 7)] = h4;
  }
  __syncthreads();
  // ---- final projection + bias + residual
  f32x4 facc[16];
  #pragma unroll
  for (int mt = 0; mt < 16; ++mt) facc[mt] = (f32x4){0, 0, 0, 0};
  #pragma unroll
  for (int ks = 0; ks < 8; ++ks) {
    f16x8 ob = *(const f16x8*)&ldsK0[iloc * 256 + (((g + 4 * ks) ^ (iloc & 7)) << 3)];
    #pragma unroll
    for (int mt = 0; mt < 16; ++mt) {
      f16x8 ah = *(const f16x8*)(woh + (16 * mt + l15) * 256 + 8 * g + 32 * ks);
      facc[mt] = MFMAH(ah, ob, facc[mt]);
    }
  }
  const int ig = i0 + iloc;
  #pragma unroll
  for (int mt = 0; mt < 16; ++mt) {
    int c0 = 16 * mt + 4 * g;
    float4 bo4 = *(const float4*)(bo + c0);
    #pragma unroll
    for (int r = 0; r < 4; ++r) {
      size_t off = ((size_t)b * C_ + c0 + r) * N_ + ig;
      out[off] = facc[mt][r] + ((const float*)&bo4)[r] + x[off];
    }
  }
}

extern "C" void kernel_launch(void* const* d_in, const int* in_sizes, int n_in,
                              void* d_out, int out_size, void* d_ws, size_t ws_size,
                              hipStream_t stream) {
  const float* x = (const float*)d_in[0];
  const float* ctx = (const float*)d_in[1];
  const float* wq = (const float*)d_in[2];
  const float* bq = (const float*)d_in[3];
  const float* wk = (const float*)d_in[4];
  const float* bk = (const float*)d_in[5];
  const float* wv = (const float*)d_in[6];
  const float* bv = (const float*)d_in[7];
  const float* wo = (const float*)d_in[8];
  const float* bo = (const float*)d_in[9];
  float* out = (float*)d_out;

  f16* ws = (f16*)d_ws;
  f16* wqh = ws;
  f16* wkh = wqh + 65536;
  f16* wvh = wkh + 65536;
  f16* woh = wvh + 65536;
  f16* KTh = woh + 65536;
  f16* Vg = KTh + (size_t)B_ * N_ * C_;

  prep_weights<<<256, 256, 0, stream>>>(wq, wk, wv, wo, wqh, wkh, wvh, woh);
  proj_kv<<<256, 256, 0, stream>>>(ctx, bk, bv, wkh, wvh, KTh, Vg);
  attn_fused<<<256, 256, 0, stream>>>(x, bq, bo, wqh, woh, KTh, Vg, out);
}